// Round 14
// baseline (6059.207 us; speedup 1.0000x reference)
//
#include <hip/hip_runtime.h>
#include <hip/hip_fp16.h>

#define N 4096
#define KX 3072
#define KZ 128
#define NBT (N / 128)               // 32 tile-rows for the MFMA dist kernel
#define NTRI2 (NBT * (NBT + 1) / 2) // 528 triangular tiles

typedef __attribute__((ext_vector_type(8))) short bf16x8;
typedef __attribute__((ext_vector_type(4))) float f32x4;

// ---------- helpers ----------
__device__ __forceinline__ short f2bf(float f) {  // RTN-even fp32 -> bf16
  unsigned u = __float_as_uint(f);
  u += 0x7fffu + ((u >> 16) & 1u);
  return (short)(u >> 16);
}

__device__ __forceinline__ unsigned umin2(unsigned a, unsigned b) { return a < b ? a : b; }

// DPP-based partial u32-min (within 16-lane rows); CTRL compile-time.
template <int CTRL>
__device__ __forceinline__ unsigned dpp_umin(unsigned x) {
  unsigned y = (unsigned)__builtin_amdgcn_update_dpp(0, (int)x, CTRL, 0xF, 0xF, true);
  return umin2(x, y);
}

#define INFK(idx) (0xFFFF0000u | (unsigned)(idx))

// per-lane min over a full row held as 16 x uint4 (64 values)
__device__ __forceinline__ unsigned rowmin64(const uint4* u) {
  unsigned bq[16];
  #pragma unroll
  for (int q = 0; q < 16; ++q)
    bq[q] = umin2(umin2(u[q].x, u[q].y), umin2(u[q].z, u[q].w));
  #pragma unroll
  for (int s = 8; s; s >>= 1)
    #pragma unroll
    for (int q = 0; q < s; ++q) bq[q] = umin2(bq[q], bq[q + s]);
  return bq[0];
}

// wave-wide u32 min -> uniform value (4 DPP stages + readlane tail)
__device__ __forceinline__ unsigned wavemin(unsigned x) {
  x = dpp_umin<0xB1>(x);   // quad_perm [1,0,3,2]
  x = dpp_umin<0x4E>(x);   // quad_perm [2,3,0,1]
  x = dpp_umin<0x141>(x);  // row_half_mirror
  x = dpp_umin<0x140>(x);  // row_mirror
  unsigned r0 = (unsigned)__builtin_amdgcn_readlane((int)x, 0);
  unsigned r1 = (unsigned)__builtin_amdgcn_readlane((int)x, 16);
  unsigned r2 = (unsigned)__builtin_amdgcn_readlane((int)x, 32);
  unsigned r3 = (unsigned)__builtin_amdgcn_readlane((int)x, 48);
  return umin2(umin2(r0, r1), umin2(r2, r3));
}

// ---------- fp32 -> bf16 conversion (8 elems/thread, grid-stride) ----------
__global__ __launch_bounds__(256) void cvt_bf16_kernel(const float* __restrict__ X,
                                                       short* __restrict__ Xb, int n8) {
  int stride = gridDim.x * 256;
  for (int i = blockIdx.x * 256 + threadIdx.x; i < n8; i += stride) {
    float4 a = *(const float4*)(X + (size_t)i * 8);
    float4 b = *(const float4*)(X + (size_t)i * 8 + 4);
    bf16x8 o;
    o[0] = f2bf(a.x); o[1] = f2bf(a.y); o[2] = f2bf(a.z); o[3] = f2bf(a.w);
    o[4] = f2bf(b.x); o[5] = f2bf(b.y); o[6] = f2bf(b.z); o[7] = f2bf(b.w);
    *(bf16x8*)(Xb + (size_t)i * 8) = o;
  }
}

// ---------- row squared norms (exact fp32) ----------
__global__ __launch_bounds__(256) void sqnorm_kernel(const float* __restrict__ X, int K,
                                                     float* __restrict__ sq) {
  int row = blockIdx.x;
  const float4* xr = (const float4*)(X + (size_t)row * K);
  float s = 0.f;
  int n4 = K >> 2;
  for (int i = threadIdx.x; i < n4; i += 256) {
    float4 v = xr[i];
    s += v.x * v.x + v.y * v.y + v.z * v.z + v.w * v.w;
  }
  for (int off = 32; off > 0; off >>= 1) s += __shfl_down(s, off);
  __shared__ float wsum[4];
  int lane = threadIdx.x & 63, w = threadIdx.x >> 6;
  if (lane == 0) wsum[w] = s;
  __syncthreads();
  if (threadIdx.x == 0) {
    float t = 0.f;
    #pragma unroll
    for (int i = 0; i < 4; ++i) t += wsum[i];
    sq[row] = t;
  }
}

// ---------- MFMA bf16 distance GEMM ----------
// KEYS=true: writes u32 argmin keys (halfbits(d)<<16)|col, diagonal = INF-key.
template <bool KEYS>
__global__ __launch_bounds__(256) void dist_mfma_kernel(const short* __restrict__ Xb, int K,
                                                        const float* __restrict__ sq,
                                                        void* __restrict__ Dout) {
  int t = blockIdx.x;
  int br = (int)((sqrtf(8.0f * (float)t + 1.0f) - 1.0f) * 0.5f);
  while ((br + 1) * (br + 2) / 2 <= t) ++br;
  while (br * (br + 1) / 2 > t) --br;
  int bc = t - br * (br + 1) / 2;
  int i0 = br * 128, j0 = bc * 128;

  __shared__ short As[128][40];
  __shared__ short Bs[128][40];

  int tid = threadIdx.x, lane = tid & 63, w = tid >> 6;
  int wr = w >> 1, wc = w & 1;
  int fr = lane & 15, fc = lane >> 4;

  f32x4 acc[4][4];
  #pragma unroll
  for (int m = 0; m < 4; ++m)
    #pragma unroll
    for (int nn = 0; nn < 4; ++nn)
      acc[m][nn] = (f32x4){0.f, 0.f, 0.f, 0.f};

  for (int k0 = 0; k0 < K; k0 += 32) {
    #pragma unroll
    for (int u = 0; u < 2; ++u) {
      int f = tid + u * 256;
      int r = f >> 2;
      int c = (f & 3) * 8;
      *(bf16x8*)&As[r][c] = *(const bf16x8*)(Xb + (size_t)(i0 + r) * K + k0 + c);
      *(bf16x8*)&Bs[r][c] = *(const bf16x8*)(Xb + (size_t)(j0 + r) * K + k0 + c);
    }
    __syncthreads();
    bf16x8 af[4], bg[4];
    #pragma unroll
    for (int m = 0; m < 4; ++m)
      af[m] = *(const bf16x8*)&As[wr * 64 + m * 16 + fr][fc * 8];
    #pragma unroll
    for (int nn = 0; nn < 4; ++nn)
      bg[nn] = *(const bf16x8*)&Bs[wc * 64 + nn * 16 + fr][fc * 8];
    #pragma unroll
    for (int m = 0; m < 4; ++m)
      #pragma unroll
      for (int nn = 0; nn < 4; ++nn)
        acc[m][nn] = __builtin_amdgcn_mfma_f32_16x16x32_bf16(af[m], bg[nn], acc[m][nn], 0, 0, 0);
    __syncthreads();
  }

  #pragma unroll
  for (int m = 0; m < 4; ++m) {
    #pragma unroll
    for (int nn = 0; nn < 4; ++nn) {
      int gj = j0 + wc * 64 + nn * 16 + fr;
      float sqj = sq[gj];
      #pragma unroll
      for (int e = 0; e < 4; ++e) {
        int gi = i0 + wr * 64 + m * 16 + fc * 4 + e;
        float d2 = sq[gi] + sqj - 2.0f * acc[m][nn][e];
        float d = sqrtf(fmaxf(d2, 0.0f));
        __half h = __float2half(d);
        if constexpr (KEYS) {
          unsigned hb = (unsigned)__half_as_ushort(h);
          unsigned* Kd = (unsigned*)Dout;
          unsigned kij = (gi == gj) ? INFK(gj) : ((hb << 16) | (unsigned)gj);
          unsigned kji = (gi == gj) ? INFK(gi) : ((hb << 16) | (unsigned)gi);
          Kd[(size_t)gi * N + gj] = kij;
          Kd[(size_t)gj * N + gi] = kji;
        } else {
          __half* D = (__half*)Dout;
          D[(size_t)gi * N + gj] = h;
          D[(size_t)gj * N + gi] = h;
        }
      }
    }
  }
}

// ---------- MST selection sequence (exact reference semantics, no par) ----------
// Each of the 8 waves redundantly loads the FULL row (L1 dedupes) -> the
// B-reduce is wave-local: no post-load LDS round-trip. The A-part (md) is
// distributed 8 nodes/thread; its cross-wave combine (slot write + barrier +
// slot read) runs entirely under the row-load latency, using a non-draining
// lgkmcnt-only barrier (inline asm; __syncthreads' vmcnt(0) would drain the
// in-flight row load). Parents are reconstructed by parent_kernel afterwards.
__global__ __launch_bounds__(512) void mst_seq_kernel(const unsigned* __restrict__ Kx,
                                                      const unsigned* __restrict__ Kz,
                                                      unsigned* __restrict__ seqx,
                                                      unsigned* __restrict__ seqz) {
  const unsigned* __restrict__ Kd = (blockIdx.x == 0) ? Kx : Kz;
  unsigned* __restrict__ seqo = (blockIdx.x == 0) ? seqx : seqz;

  int tid = threadIdx.x, lane = tid & 63, w = tid >> 6;
  unsigned ob0 = (unsigned)((2 * w) * 256 + lane * 4);  // owned slice offsets
  unsigned ob1 = ob0 + 256;

  __shared__ unsigned skey[2][8];
  __shared__ unsigned seqlds[N - 1];

  unsigned mdk[8];
  unsigned j;
  {
    // prologue: row 0 (md init == row 0 with diag INFK -> node 0 in tree)
    uint4 u[16];
    #pragma unroll
    for (int q = 0; q < 16; ++q)
      u[q] = *(const uint4*)(Kd + q * 256 + lane * 4);
    uint4 v0 = *(const uint4*)(Kd + ob0);
    uint4 v1 = *(const uint4*)(Kd + ob1);
    unsigned key = wavemin(rowmin64(u));   // identical in every wave
    j = key & 0xFFFFu;
    mdk[0] = v0.x; mdk[1] = v0.y; mdk[2] = v0.z; mdk[3] = v0.w;
    mdk[4] = v1.x; mdk[5] = v1.y; mdk[6] = v1.z; mdk[7] = v1.w;
  }

  unsigned prk[8];
  #pragma unroll
  for (int k = 0; k < 8; ++k) prk[k] = 0xFFFFFFFFu;
  unsigned jprev = 0xFFFFFFFFu;  // sentinel: matches no idx

  for (int t = 0; t < N - 1; ++t) {
    int p = t & 1;

    // 1. issue full-row load (16 x dwordx4) + owned slice (2 more); pin order
    const unsigned* row = Kd + (size_t)j * N;
    uint4 u[16];
    #pragma unroll
    for (int q = 0; q < 16; ++q)
      u[q] = *(const uint4*)(row + q * 256 + lane * 4);
    uint4 v0 = *(const uint4*)(row + ob0);
    uint4 v1 = *(const uint4*)(row + ob1);
    __builtin_amdgcn_sched_barrier(0);

    // 2. A-part (no dependence on in-flight load): deferred update with prev
    //    row + re-INF at j_{t-1} + eager INF at j_t, then tree
    #pragma unroll
    for (int k = 0; k < 8; ++k) {
      unsigned idx = (k < 4) ? (ob0 + (unsigned)k) : (ob1 + (unsigned)(k - 4));
      unsigned m = umin2(mdk[k], prk[k]);
      m = (idx == jprev) ? INFK(idx) : m;
      m = (idx == j) ? INFK(idx) : m;
      mdk[k] = m;
    }
    {
      unsigned a = umin2(umin2(umin2(mdk[0], mdk[1]), umin2(mdk[2], mdk[3])),
                         umin2(umin2(mdk[4], mdk[5]), umin2(mdk[6], mdk[7])));
      unsigned aw = wavemin(a);
      if (lane == 0) skey[p][w] = aw;
    }
    if (tid == 0) seqlds[t] = j;

    // 3. non-draining barrier (lgkm only; row load stays in flight)
    asm volatile("s_waitcnt lgkmcnt(0)\n\ts_barrier" ::: "memory");

    // 4. read 8 A-slots (still under load) and combine
    uint4 A0 = ((const uint4*)&skey[p][0])[0];
    uint4 A1 = ((const uint4*)&skey[p][0])[1];
    unsigned ag = umin2(umin2(umin2(A0.x, A0.y), umin2(A0.z, A0.w)),
                        umin2(umin2(A1.x, A1.y), umin2(A1.z, A1.w)));

    // 5. B-part: wave-local full-row min (vmcnt wait lands here)
    unsigned bg = wavemin(rowmin64(u));

    // 6. next selection (uniform scalar), bookkeeping, carry owned slice
    unsigned key = umin2(ag, bg);
    jprev = j;
    j = key & 0xFFFFu;
    prk[0] = v0.x; prk[1] = v0.y; prk[2] = v0.z; prk[3] = v0.w;
    prk[4] = v1.x; prk[5] = v1.y; prk[6] = v1.z; prk[7] = v1.w;
  }

  __syncthreads();
  for (int e = tid; e < N - 1; e += 512) seqo[e] = seqlds[e];
}

// ---------- parent reconstruction (parallel replay of reference par updates) ----------
// Thread per node w: walk the selection sequence, tracking running md/par for
// w exactly as the reference does (incl. resurrection; md reset to "INF" when
// w itself is selected; diagonal INFK suppresses only the self-parent, which
// provably never reaches an edge record). Coalesced: at each step all threads
// of a block read consecutive elements of row seq[t].
__global__ __launch_bounds__(512) void parent_kernel(const unsigned* __restrict__ Kx,
                                                     const unsigned* __restrict__ Kz,
                                                     const unsigned* __restrict__ seqx,
                                                     const unsigned* __restrict__ seqz,
                                                     int2* __restrict__ ex,
                                                     int2* __restrict__ ez) {
  int b = blockIdx.x;             // 0..15: 8 blocks per matrix
  bool isz = (b >= 8);
  const unsigned* __restrict__ Kd = isz ? Kz : Kx;
  const unsigned* __restrict__ seq = isz ? seqz : seqx;
  int2* __restrict__ edges = isz ? ez : ex;
  unsigned wn = (unsigned)(((b & 7) * 512) + threadIdx.x);  // node id

  __shared__ unsigned sseq[N - 1];
  for (int i = threadIdx.x; i < N - 1; i += 512) sseq[i] = seq[i];
  __syncthreads();

  unsigned md = Kd[wn];  // row 0; diag INFK gives md[0]="INF"
  int par = 0;
  #pragma unroll 4
  for (int t = 0; t < N - 1; ++t) {
    unsigned r = sseq[t];
    if (r == wn) edges[t] = make_int2(par, (int)wn);  // edge before this row's update
    unsigned v = Kd[(size_t)r * N + wn];
    if (v < md) { md = v; par = (int)r; }
    if (r == wn) md = 0xFFFFFFFFu;  // .at[j].set(inf) after the min-update
  }
}

// ---------- MST on half distances (round-10 proven fallback) ----------
__global__ __launch_bounds__(512) void mst_half_kernel(const __half* __restrict__ Dx,
                                                       const __half* __restrict__ Dz,
                                                       int2* __restrict__ ex,
                                                       int2* __restrict__ ez) {
  const __half* __restrict__ D = (blockIdx.x == 0) ? Dx : Dz;
  int2* __restrict__ edges = (blockIdx.x == 0) ? ex : ez;

  int tid = threadIdx.x;
  int lane = tid & 63;
  int w = tid >> 6;
  int base = tid * 8;

  unsigned mdk0, mdk1, mdk2, mdk3, mdk4, mdk5, mdk6, mdk7;
  int par0 = 0, par1 = 0, par2 = 0, par3 = 0, par4 = 0, par5 = 0, par6 = 0, par7 = 0;
  {
    uint4 u = *(const uint4*)(D + base);
    mdk0 = (u.x << 16) | (unsigned)(base + 0);
    mdk1 = (u.x & 0xffff0000u) | (unsigned)(base + 1);
    mdk2 = (u.y << 16) | (unsigned)(base + 2);
    mdk3 = (u.y & 0xffff0000u) | (unsigned)(base + 3);
    mdk4 = (u.z << 16) | (unsigned)(base + 4);
    mdk5 = (u.z & 0xffff0000u) | (unsigned)(base + 5);
    mdk6 = (u.w << 16) | (unsigned)(base + 6);
    mdk7 = (u.w & 0xffff0000u) | (unsigned)(base + 7);
  }
  if (tid == 0) mdk0 = INFK(0);

  __shared__ unsigned skey[2][8];
  __shared__ uint2 eld[N - 1];

  int j;
  {
    unsigned x = umin2(umin2(umin2(mdk0, mdk1), umin2(mdk2, mdk3)),
                       umin2(umin2(mdk4, mdk5), umin2(mdk6, mdk7)));
    unsigned wm = wavemin(x);
    if (lane == 0) skey[1][w] = wm;
    __syncthreads();
    uint4 A = ((const uint4*)&skey[1][0])[0];
    uint4 B = ((const uint4*)&skey[1][0])[1];
    unsigned k = umin2(umin2(umin2(A.x, A.y), umin2(A.z, A.w)),
                       umin2(umin2(B.x, B.y), umin2(B.z, B.w)));
    j = (int)(k & 0xFFFFu);
  }

  unsigned prk0 = 0xFFFFFFFFu, prk1 = 0xFFFFFFFFu, prk2 = 0xFFFFFFFFu, prk3 = 0xFFFFFFFFu,
           prk4 = 0xFFFFFFFFu, prk5 = 0xFFFFFFFFu, prk6 = 0xFFFFFFFFu, prk7 = 0xFFFFFFFFu;
  int jp = 0, jtprev = -1, jlprev = 0;

  for (int t = 0; t < N - 1; ++t) {
    int p = t & 1;
    int jt = j >> 3, jl = j & 7;

    uint4 u = *(const uint4*)(D + (size_t)j * N + base);
    __builtin_amdgcn_sched_barrier(0);

    #define DUPD(q) { bool up_ = prk##q < mdk##q; mdk##q = up_ ? prk##q : mdk##q; par##q = up_ ? jp : par##q; }
    DUPD(0) DUPD(1) DUPD(2) DUPD(3) DUPD(4) DUPD(5) DUPD(6) DUPD(7)
    #undef DUPD
    if (jtprev == tid) {
      if      (jlprev == 0) mdk0 = INFK(base + 0);
      else if (jlprev == 1) mdk1 = INFK(base + 1);
      else if (jlprev == 2) mdk2 = INFK(base + 2);
      else if (jlprev == 3) mdk3 = INFK(base + 3);
      else if (jlprev == 4) mdk4 = INFK(base + 4);
      else if (jlprev == 5) mdk5 = INFK(base + 5);
      else if (jlprev == 6) mdk6 = INFK(base + 6);
      else                  mdk7 = INFK(base + 7);
    }

    if (jt == tid) {
      int pj = (jl == 0) ? par0 : (jl == 1) ? par1 : (jl == 2) ? par2 :
               (jl == 3) ? par3 : (jl == 4) ? par4 : (jl == 5) ? par5 :
               (jl == 6) ? par6 : par7;
      eld[t] = make_uint2((unsigned)pj, (unsigned)j);
    }

    if (jt == tid) {
      if      (jl == 0) mdk0 = INFK(base + 0);
      else if (jl == 1) mdk1 = INFK(base + 1);
      else if (jl == 2) mdk2 = INFK(base + 2);
      else if (jl == 3) mdk3 = INFK(base + 3);
      else if (jl == 4) mdk4 = INFK(base + 4);
      else if (jl == 5) mdk5 = INFK(base + 5);
      else if (jl == 6) mdk6 = INFK(base + 6);
      else              mdk7 = INFK(base + 7);
    }

    unsigned ak = umin2(umin2(umin2(mdk0, mdk1), umin2(mdk2, mdk3)),
                        umin2(umin2(mdk4, mdk5), umin2(mdk6, mdk7)));

    prk0 = (u.x << 16) | (unsigned)(base + 0);
    prk1 = (u.x & 0xffff0000u) | (unsigned)(base + 1);
    prk2 = (u.y << 16) | (unsigned)(base + 2);
    prk3 = (u.y & 0xffff0000u) | (unsigned)(base + 3);
    prk4 = (u.z << 16) | (unsigned)(base + 4);
    prk5 = (u.z & 0xffff0000u) | (unsigned)(base + 5);
    prk6 = (u.w << 16) | (unsigned)(base + 6);
    prk7 = (u.w & 0xffff0000u) | (unsigned)(base + 7);
    {
      bool self = (jt == tid);
      unsigned b0 = (self && jl == 0) ? 0xFFFFFFFFu : prk0;
      unsigned b1 = (self && jl == 1) ? 0xFFFFFFFFu : prk1;
      unsigned b2 = (self && jl == 2) ? 0xFFFFFFFFu : prk2;
      unsigned b3 = (self && jl == 3) ? 0xFFFFFFFFu : prk3;
      unsigned b4 = (self && jl == 4) ? 0xFFFFFFFFu : prk4;
      unsigned b5 = (self && jl == 5) ? 0xFFFFFFFFu : prk5;
      unsigned b6 = (self && jl == 6) ? 0xFFFFFFFFu : prk6;
      unsigned b7 = (self && jl == 7) ? 0xFFFFFFFFu : prk7;
      unsigned bk = umin2(umin2(umin2(b0, b1), umin2(b2, b3)),
                          umin2(umin2(b4, b5), umin2(b6, b7)));
      unsigned wm = wavemin(umin2(ak, bk));
      if (lane == 0) skey[p][w] = wm;
    }

    jp = j; jtprev = jt; jlprev = jl;

    __syncthreads();
    uint4 A = ((const uint4*)&skey[p][0])[0];
    uint4 B = ((const uint4*)&skey[p][0])[1];
    unsigned k = umin2(umin2(umin2(A.x, A.y), umin2(A.z, A.w)),
                       umin2(umin2(B.x, B.y), umin2(B.z, B.w)));
    j = (int)(k & 0xFFFFu);
  }

  __syncthreads();
  for (int e = tid; e < N - 1; e += 512) {
    uint2 v = eld[e];
    edges[e] = make_int2((int)v.x, (int)v.y);
  }
}

// ---------- final loss (KEYS=true reads u32 key matrices, else half) ----------
template <bool KEYS>
__global__ __launch_bounds__(1024) void loss_kernel(const void* __restrict__ DxV,
                                                    const void* __restrict__ DzV,
                                                    const int2* __restrict__ ex,
                                                    const int2* __restrict__ ez,
                                                    float* __restrict__ out) {
  int tid = threadIdx.x;
  float s = 0.f;
  const int M = N - 1;
  for (int e = tid; e < 2 * M; e += 1024) {
    int2 uv = (e < M) ? ex[e] : ez[e - M];
    size_t off = (size_t)uv.x * N + uv.y;
    float dx, dz;
    if constexpr (KEYS) {
      dx = __half2float(__ushort_as_half((unsigned short)(((const unsigned*)DxV)[off] >> 16)));
      dz = __half2float(__ushort_as_half((unsigned short)(((const unsigned*)DzV)[off] >> 16)));
    } else {
      dx = __half2float(((const __half*)DxV)[off]);
      dz = __half2float(((const __half*)DzV)[off]);
    }
    float d = dx - dz;
    s += d * d;
  }
  for (int off = 32; off > 0; off >>= 1) s += __shfl_down(s, off);
  __shared__ float wsum[16];
  int lane = tid & 63, w = tid >> 6;
  if (lane == 0) wsum[w] = s;
  __syncthreads();
  if (tid == 0) {
    float t = 0.f;
    #pragma unroll
    for (int i = 0; i < 16; ++i) t += wsum[i];
    out[0] = 0.5f * t;
  }
}

// ---------- launch ----------
extern "C" void kernel_launch(void* const* d_in, const int* in_sizes, int n_in,
                              void* d_out, int out_size, void* d_ws, size_t ws_size,
                              hipStream_t stream) {
  const float* x = (const float*)d_in[0];
  const float* z = (const float*)d_in[1];
  float* out = (float*)d_out;
  char* ws = (char*)d_ws;

  size_t need_keys = (size_t)2 * N * N * 4
                   + (size_t)N * KX * 2 + (size_t)N * KZ * 2
                   + (size_t)2 * N * 4
                   + (size_t)2 * (N - 1) * 8;

  if (ws_size >= need_keys) {
    unsigned* Kx = (unsigned*)ws;                   // 64 MB
    unsigned* Kz = Kx + (size_t)N * N;              // 64 MB
    short* Xb = (short*)(Kz + (size_t)N * N);       // 24 MB
    short* Zb = Xb + (size_t)N * KX;                // 1 MB
    float* sqx = (float*)(Zb + (size_t)N * KZ);
    float* sqz = sqx + N;
    int2* ex = (int2*)(sqz + N);
    int2* ez = ex + (N - 1);
    // seq arrays alias Xb (free after the GEMMs read it; rewritten next launch)
    unsigned* seqx = (unsigned*)Xb;
    unsigned* seqz = seqx + (N - 1);

    cvt_bf16_kernel<<<2048, 256, 0, stream>>>(x, Xb, N * KX / 8);
    cvt_bf16_kernel<<<256, 256, 0, stream>>>(z, Zb, N * KZ / 8);
    sqnorm_kernel<<<N, 256, 0, stream>>>(x, KX, sqx);
    sqnorm_kernel<<<N, 256, 0, stream>>>(z, KZ, sqz);
    dist_mfma_kernel<true><<<NTRI2, 256, 0, stream>>>(Xb, KX, sqx, Kx);
    dist_mfma_kernel<true><<<NTRI2, 256, 0, stream>>>(Zb, KZ, sqz, Kz);
    mst_seq_kernel<<<2, 512, 0, stream>>>(Kx, Kz, seqx, seqz);
    parent_kernel<<<16, 512, 0, stream>>>(Kx, Kz, seqx, seqz, ex, ez);
    loss_kernel<true><<<1, 1024, 0, stream>>>(Kx, Kz, ex, ez, out);
  } else {
    __half* Dx = (__half*)ws;
    __half* Dz = Dx + (size_t)N * N;
    short* Xb = (short*)(Dz + (size_t)N * N);
    short* Zb = Xb + (size_t)N * KX;
    float* sqx = (float*)(Zb + (size_t)N * KZ);
    float* sqz = sqx + N;
    int2* ex = (int2*)(sqz + N);
    int2* ez = ex + (N - 1);

    cvt_bf16_kernel<<<2048, 256, 0, stream>>>(x, Xb, N * KX / 8);
    cvt_bf16_kernel<<<256, 256, 0, stream>>>(z, Zb, N * KZ / 8);
    sqnorm_kernel<<<N, 256, 0, stream>>>(x, KX, sqx);
    sqnorm_kernel<<<N, 256, 0, stream>>>(z, KZ, sqz);
    dist_mfma_kernel<false><<<NTRI2, 256, 0, stream>>>(Xb, KX, sqx, Dx);
    dist_mfma_kernel<false><<<NTRI2, 256, 0, stream>>>(Zb, KZ, sqz, Dz);
    mst_half_kernel<<<2, 512, 0, stream>>>(Dx, Dz, ex, ez);
    loss_kernel<false><<<1, 1024, 0, stream>>>(Dx, Dz, ex, ez, out);
  }
}

// Round 15
// 5896.560 us; speedup vs baseline: 1.0276x; 1.0276x over previous
//
#include <hip/hip_runtime.h>
#include <hip/hip_fp16.h>

#define N 4096
#define KX 3072
#define KZ 128
#define NBT (N / 128)               // 32 tile-rows for the MFMA dist kernel
#define NTRI2 (NBT * (NBT + 1) / 2) // 528 triangular tiles

typedef __attribute__((ext_vector_type(8))) short bf16x8;
typedef __attribute__((ext_vector_type(4))) float f32x4;

// ---------- helpers ----------
__device__ __forceinline__ short f2bf(float f) {  // RTN-even fp32 -> bf16
  unsigned u = __float_as_uint(f);
  u += 0x7fffu + ((u >> 16) & 1u);
  return (short)(u >> 16);
}

__device__ __forceinline__ unsigned umin2(unsigned a, unsigned b) { return a < b ? a : b; }

template <int CTRL>
__device__ __forceinline__ unsigned dpp_umin(unsigned x) {
  unsigned y = (unsigned)__builtin_amdgcn_update_dpp(0, (int)x, CTRL, 0xF, 0xF, true);
  return umin2(x, y);
}

#define INFK(idx) (0xFFFF0000u | (unsigned)(idx))

// wave-wide u32 min -> uniform value (4 DPP stages + readlane tail)
__device__ __forceinline__ unsigned wavemin(unsigned x) {
  x = dpp_umin<0xB1>(x);   // quad_perm [1,0,3,2]
  x = dpp_umin<0x4E>(x);   // quad_perm [2,3,0,1]
  x = dpp_umin<0x141>(x);  // row_half_mirror
  x = dpp_umin<0x140>(x);  // row_mirror
  unsigned r0 = (unsigned)__builtin_amdgcn_readlane((int)x, 0);
  unsigned r1 = (unsigned)__builtin_amdgcn_readlane((int)x, 16);
  unsigned r2 = (unsigned)__builtin_amdgcn_readlane((int)x, 32);
  unsigned r3 = (unsigned)__builtin_amdgcn_readlane((int)x, 48);
  return umin2(umin2(r0, r1), umin2(r2, r3));
}

// per-lane min over 16 uint4 (64 values), all static indexing
__device__ __forceinline__ unsigned treemin16(const uint4 m[16]) {
  unsigned a[16];
  #pragma unroll
  for (int q = 0; q < 16; ++q)
    a[q] = umin2(umin2(m[q].x, m[q].y), umin2(m[q].z, m[q].w));
  #pragma unroll
  for (int s = 8; s; s >>= 1)
    #pragma unroll
    for (int q = 0; q < s; ++q) a[q] = umin2(a[q], a[q + s]);
  return a[0];
}

// store INF-key at column C of the distributed md (layout: md[q] holds
// columns q*256 + lane*4 + e). q,e are wave-uniform -> scalar branches;
// only one lane writes. Static md indexing everywhere (rule #20).
__device__ __forceinline__ void set_inf(uint4 md[16], unsigned C, unsigned lane) {
  if (C >= 0x10000u) return;  // sentinel (first iteration)
  unsigned q = C >> 8, lt = (C >> 2) & 63, e = C & 3;
  unsigned iv = INFK(C);
  #pragma unroll
  for (unsigned qq = 0; qq < 16; ++qq) {
    if (qq == q && lane == lt) {
      if      (e == 0) md[qq].x = iv;
      else if (e == 1) md[qq].y = iv;
      else if (e == 2) md[qq].z = iv;
      else             md[qq].w = iv;
    }
  }
}

// ---------- fp32 -> bf16 conversion (8 elems/thread, grid-stride) ----------
__global__ __launch_bounds__(256) void cvt_bf16_kernel(const float* __restrict__ X,
                                                       short* __restrict__ Xb, int n8) {
  int stride = gridDim.x * 256;
  for (int i = blockIdx.x * 256 + threadIdx.x; i < n8; i += stride) {
    float4 a = *(const float4*)(X + (size_t)i * 8);
    float4 b = *(const float4*)(X + (size_t)i * 8 + 4);
    bf16x8 o;
    o[0] = f2bf(a.x); o[1] = f2bf(a.y); o[2] = f2bf(a.z); o[3] = f2bf(a.w);
    o[4] = f2bf(b.x); o[5] = f2bf(b.y); o[6] = f2bf(b.z); o[7] = f2bf(b.w);
    *(bf16x8*)(Xb + (size_t)i * 8) = o;
  }
}

// ---------- row squared norms (exact fp32) ----------
__global__ __launch_bounds__(256) void sqnorm_kernel(const float* __restrict__ X, int K,
                                                     float* __restrict__ sq) {
  int row = blockIdx.x;
  const float4* xr = (const float4*)(X + (size_t)row * K);
  float s = 0.f;
  int n4 = K >> 2;
  for (int i = threadIdx.x; i < n4; i += 256) {
    float4 v = xr[i];
    s += v.x * v.x + v.y * v.y + v.z * v.z + v.w * v.w;
  }
  for (int off = 32; off > 0; off >>= 1) s += __shfl_down(s, off);
  __shared__ float wsum[4];
  int lane = threadIdx.x & 63, w = threadIdx.x >> 6;
  if (lane == 0) wsum[w] = s;
  __syncthreads();
  if (threadIdx.x == 0) {
    float t = 0.f;
    #pragma unroll
    for (int i = 0; i < 4; ++i) t += wsum[i];
    sq[row] = t;
  }
}

// ---------- MFMA bf16 distance GEMM -> u32 argmin keys ----------
// K[i][j] = (halfbits(d_ij)<<16)|j, diagonal stored as INF-key (r13-proven).
__global__ __launch_bounds__(256) void dist_mfma_kernel(const short* __restrict__ Xb, int K,
                                                        const float* __restrict__ sq,
                                                        unsigned* __restrict__ Kd) {
  int t = blockIdx.x;
  int br = (int)((sqrtf(8.0f * (float)t + 1.0f) - 1.0f) * 0.5f);
  while ((br + 1) * (br + 2) / 2 <= t) ++br;
  while (br * (br + 1) / 2 > t) --br;
  int bc = t - br * (br + 1) / 2;
  int i0 = br * 128, j0 = bc * 128;

  __shared__ short As[128][40];
  __shared__ short Bs[128][40];

  int tid = threadIdx.x, lane = tid & 63, w = tid >> 6;
  int wr = w >> 1, wc = w & 1;
  int fr = lane & 15, fc = lane >> 4;

  f32x4 acc[4][4];
  #pragma unroll
  for (int m = 0; m < 4; ++m)
    #pragma unroll
    for (int nn = 0; nn < 4; ++nn)
      acc[m][nn] = (f32x4){0.f, 0.f, 0.f, 0.f};

  for (int k0 = 0; k0 < K; k0 += 32) {
    #pragma unroll
    for (int u = 0; u < 2; ++u) {
      int f = tid + u * 256;
      int r = f >> 2;
      int c = (f & 3) * 8;
      *(bf16x8*)&As[r][c] = *(const bf16x8*)(Xb + (size_t)(i0 + r) * K + k0 + c);
      *(bf16x8*)&Bs[r][c] = *(const bf16x8*)(Xb + (size_t)(j0 + r) * K + k0 + c);
    }
    __syncthreads();
    bf16x8 af[4], bg[4];
    #pragma unroll
    for (int m = 0; m < 4; ++m)
      af[m] = *(const bf16x8*)&As[wr * 64 + m * 16 + fr][fc * 8];
    #pragma unroll
    for (int nn = 0; nn < 4; ++nn)
      bg[nn] = *(const bf16x8*)&Bs[wc * 64 + nn * 16 + fr][fc * 8];
    #pragma unroll
    for (int m = 0; m < 4; ++m)
      #pragma unroll
      for (int nn = 0; nn < 4; ++nn)
        acc[m][nn] = __builtin_amdgcn_mfma_f32_16x16x32_bf16(af[m], bg[nn], acc[m][nn], 0, 0, 0);
    __syncthreads();
  }

  #pragma unroll
  for (int m = 0; m < 4; ++m) {
    #pragma unroll
    for (int nn = 0; nn < 4; ++nn) {
      int gj = j0 + wc * 64 + nn * 16 + fr;
      float sqj = sq[gj];
      #pragma unroll
      for (int e = 0; e < 4; ++e) {
        int gi = i0 + wr * 64 + m * 16 + fc * 4 + e;
        float d2 = sq[gi] + sqj - 2.0f * acc[m][nn][e];
        float d = sqrtf(fmaxf(d2, 0.0f));
        unsigned hb = (unsigned)__half_as_ushort(__float2half(d));
        unsigned kij = (gi == gj) ? INFK(gj) : ((hb << 16) | (unsigned)gj);
        unsigned kji = (gi == gj) ? INFK(gi) : ((hb << 16) | (unsigned)gi);
        Kd[(size_t)gi * N + gj] = kij;
        Kd[(size_t)gj * N + gi] = kji;
      }
    }
  }
}

// ---------- MST selection sequence: SINGLE WAVE per matrix ----------
// 64 lanes x 64 nodes/lane; md/prk/u all in registers (~230 VGPR, 1 wave/SIMD
// so the 512-VGPR budget applies). No LDS slots, no barrier, no cross-wave
// traffic: per step the entire argmin is 63 umin (A, under load) + per-q
// B mins consumed in load-arrival order + ONE fused wavemin. Deferred-update
// + eager-INF scheme is r13-proven; diag INF-key makes row self-masking free.
// Parents reconstructed by parent_kernel (r14-proven).
__global__ __launch_bounds__(64) void mst_seq1_kernel(const unsigned* __restrict__ Kx,
                                                      const unsigned* __restrict__ Kz,
                                                      unsigned* __restrict__ seqx,
                                                      unsigned* __restrict__ seqz) {
  const unsigned* __restrict__ Kd = (blockIdx.x == 0) ? Kx : Kz;
  unsigned* __restrict__ seqo = (blockIdx.x == 0) ? seqx : seqz;
  unsigned lane = threadIdx.x;   // 0..63
  unsigned co = lane * 4;        // column offset within each 256-wide chunk

  __shared__ unsigned seqlds[N - 1];

  uint4 md[16];
  #pragma unroll
  for (int q = 0; q < 16; ++q)
    md[q] = *(const uint4*)(Kd + q * 256 + co);   // row 0; diag INFK -> node 0 in tree

  unsigned j = wavemin(treemin16(md)) & 0xFFFFu;

  uint4 prk[16];
  #pragma unroll
  for (int q = 0; q < 16; ++q) prk[q] = make_uint4(~0u, ~0u, ~0u, ~0u);
  unsigned jprev = 0xFFFFFFFFu;  // sentinel

  for (int t = 0; t < N - 1; ++t) {
    // 1. issue the full-row load (16 x dwordx4, coalesced, 16 KB); pin order
    const unsigned* row = Kd + (size_t)j * N;
    uint4 u[16];
    #pragma unroll
    for (int q = 0; q < 16; ++q)
      u[q] = *(const uint4*)(row + q * 256 + co);
    __builtin_amdgcn_sched_barrier(0);

    // 2. record selection
    if (lane == 0) seqlds[t] = j;

    // 3. deferred update with previous row, then INF at j_{t-1}, then eager
    //    INF at j_t (r13-proven order) — all under the load
    #pragma unroll
    for (int q = 0; q < 16; ++q) {
      md[q].x = umin2(md[q].x, prk[q].x);
      md[q].y = umin2(md[q].y, prk[q].y);
      md[q].z = umin2(md[q].z, prk[q].z);
      md[q].w = umin2(md[q].w, prk[q].w);
    }
    set_inf(md, jprev, lane);
    set_inf(md, j, lane);

    // 4. A-tree over md (under load)
    unsigned ak = treemin16(md);

    // 5. B: per-q mins in load-arrival order, then tree (vmcnt lands here)
    unsigned bq[16];
    #pragma unroll
    for (int q = 0; q < 16; ++q)
      bq[q] = umin2(umin2(u[q].x, u[q].y), umin2(u[q].z, u[q].w));
    #pragma unroll
    for (int s = 8; s; s >>= 1)
      #pragma unroll
      for (int q2 = 0; q2 < s; ++q2) bq[q2] = umin2(bq[q2], bq[q2 + s]);

    // 6. ONE wavemin for A and B fused; next selection
    jprev = j;
    j = wavemin(umin2(ak, bq[0])) & 0xFFFFu;

    // 7. carry row for next step's deferred update
    #pragma unroll
    for (int q = 0; q < 16; ++q) prk[q] = u[q];
  }

  for (unsigned e = lane; e < N - 1; e += 64) seqo[e] = seqlds[e];
}

// ---------- parent reconstruction (r14-proven parallel replay) ----------
__global__ __launch_bounds__(512) void parent_kernel(const unsigned* __restrict__ Kx,
                                                     const unsigned* __restrict__ Kz,
                                                     const unsigned* __restrict__ seqx,
                                                     const unsigned* __restrict__ seqz,
                                                     int2* __restrict__ ex,
                                                     int2* __restrict__ ez) {
  int b = blockIdx.x;             // 0..15: 8 blocks per matrix
  bool isz = (b >= 8);
  const unsigned* __restrict__ Kd = isz ? Kz : Kx;
  const unsigned* __restrict__ seq = isz ? seqz : seqx;
  int2* __restrict__ edges = isz ? ez : ex;
  unsigned wn = (unsigned)(((b & 7) * 512) + threadIdx.x);  // node id

  __shared__ unsigned sseq[N - 1];
  for (int i = threadIdx.x; i < N - 1; i += 512) sseq[i] = seq[i];
  __syncthreads();

  unsigned md = Kd[wn];  // row 0; diag INFK gives md[0]="INF"
  int par = 0;
  #pragma unroll 4
  for (int t = 0; t < N - 1; ++t) {
    unsigned r = sseq[t];
    if (r == wn) edges[t] = make_int2(par, (int)wn);  // edge before this row's update
    unsigned v = Kd[(size_t)r * N + wn];
    if (v < md) { md = v; par = (int)r; }
    if (r == wn) md = 0xFFFFFFFFu;  // .at[j].set(inf) after the min-update
  }
}

// ---------- final loss (reads u32 key matrices) ----------
__global__ __launch_bounds__(1024) void loss_kernel(const unsigned* __restrict__ KxM,
                                                    const unsigned* __restrict__ KzM,
                                                    const int2* __restrict__ ex,
                                                    const int2* __restrict__ ez,
                                                    float* __restrict__ out) {
  int tid = threadIdx.x;
  float s = 0.f;
  const int M = N - 1;
  for (int e = tid; e < 2 * M; e += 1024) {
    int2 uv = (e < M) ? ex[e] : ez[e - M];
    size_t off = (size_t)uv.x * N + uv.y;
    float dx = __half2float(__ushort_as_half((unsigned short)(KxM[off] >> 16)));
    float dz = __half2float(__ushort_as_half((unsigned short)(KzM[off] >> 16)));
    float d = dx - dz;
    s += d * d;
  }
  for (int off = 32; off > 0; off >>= 1) s += __shfl_down(s, off);
  __shared__ float wsum[16];
  int lane = tid & 63, w = tid >> 6;
  if (lane == 0) wsum[w] = s;
  __syncthreads();
  if (tid == 0) {
    float t = 0.f;
    #pragma unroll
    for (int i = 0; i < 16; ++i) t += wsum[i];
    out[0] = 0.5f * t;
  }
}

// ---------- launch ----------
extern "C" void kernel_launch(void* const* d_in, const int* in_sizes, int n_in,
                              void* d_out, int out_size, void* d_ws, size_t ws_size,
                              hipStream_t stream) {
  const float* x = (const float*)d_in[0];
  const float* z = (const float*)d_in[1];
  float* out = (float*)d_out;
  char* ws = (char*)d_ws;

  unsigned* Kx = (unsigned*)ws;                   // 64 MB
  unsigned* Kz = Kx + (size_t)N * N;              // 64 MB
  short* Xb = (short*)(Kz + (size_t)N * N);       // 24 MB
  short* Zb = Xb + (size_t)N * KX;                // 1 MB
  float* sqx = (float*)(Zb + (size_t)N * KZ);
  float* sqz = sqx + N;
  int2* ex = (int2*)(sqz + N);
  int2* ez = ex + (N - 1);
  // seq arrays alias Xb (free after the GEMMs read it; rewritten next launch)
  unsigned* seqx = (unsigned*)Xb;
  unsigned* seqz = seqx + (N - 1);

  cvt_bf16_kernel<<<2048, 256, 0, stream>>>(x, Xb, N * KX / 8);
  cvt_bf16_kernel<<<256, 256, 0, stream>>>(z, Zb, N * KZ / 8);
  sqnorm_kernel<<<N, 256, 0, stream>>>(x, KX, sqx);
  sqnorm_kernel<<<N, 256, 0, stream>>>(z, KZ, sqz);
  dist_mfma_kernel<<<NTRI2, 256, 0, stream>>>(Xb, KX, sqx, Kx);
  dist_mfma_kernel<<<NTRI2, 256, 0, stream>>>(Zb, KZ, sqz, Kz);
  mst_seq1_kernel<<<2, 64, 0, stream>>>(Kx, Kz, seqx, seqz);
  parent_kernel<<<16, 512, 0, stream>>>(Kx, Kz, seqx, seqz, ex, ez);
  loss_kernel<<<1, 1024, 0, stream>>>(Kx, Kz, ex, ez, out);
}

// Round 16
// 5537.201 us; speedup vs baseline: 1.0943x; 1.0649x over previous
//
#include <hip/hip_runtime.h>
#include <hip/hip_fp16.h>

#define N 4096
#define KX 3072
#define KZ 128
#define NBT (N / 128)               // 32 tile-rows for the MFMA dist kernel
#define NTRI2 (NBT * (NBT + 1) / 2) // 528 triangular tiles

typedef __attribute__((ext_vector_type(8))) short bf16x8;
typedef __attribute__((ext_vector_type(4))) float f32x4;

// ---------- helpers ----------
__device__ __forceinline__ short f2bf(float f) {  // RTN-even fp32 -> bf16
  unsigned u = __float_as_uint(f);
  u += 0x7fffu + ((u >> 16) & 1u);
  return (short)(u >> 16);
}

__device__ __forceinline__ unsigned umin2(unsigned a, unsigned b) { return a < b ? a : b; }

template <int CTRL>
__device__ __forceinline__ unsigned dpp_umin(unsigned x) {
  unsigned y = (unsigned)__builtin_amdgcn_update_dpp(0, (int)x, CTRL, 0xF, 0xF, true);
  return umin2(x, y);
}

#define INFK(idx) (0xFFFF0000u | (unsigned)(idx))

// wave-wide u32 min -> uniform value (4 DPP stages + readlane tail)
__device__ __forceinline__ unsigned wavemin(unsigned x) {
  x = dpp_umin<0xB1>(x);   // quad_perm [1,0,3,2]
  x = dpp_umin<0x4E>(x);   // quad_perm [2,3,0,1]
  x = dpp_umin<0x141>(x);  // row_half_mirror
  x = dpp_umin<0x140>(x);  // row_mirror
  unsigned r0 = (unsigned)__builtin_amdgcn_readlane((int)x, 0);
  unsigned r1 = (unsigned)__builtin_amdgcn_readlane((int)x, 16);
  unsigned r2 = (unsigned)__builtin_amdgcn_readlane((int)x, 32);
  unsigned r3 = (unsigned)__builtin_amdgcn_readlane((int)x, 48);
  return umin2(umin2(r0, r1), umin2(r2, r3));
}

// per-lane min over 16 uint4 (64 values), all static indexing
__device__ __forceinline__ unsigned treemin16(const uint4 m[16]) {
  unsigned a[16];
  #pragma unroll
  for (int q = 0; q < 16; ++q)
    a[q] = umin2(umin2(m[q].x, m[q].y), umin2(m[q].z, m[q].w));
  #pragma unroll
  for (int s = 8; s; s >>= 1)
    #pragma unroll
    for (int q = 0; q < s; ++q) a[q] = umin2(a[q], a[q + s]);
  return a[0];
}

// store INF-key at column C of the distributed md (layout: md[q] holds
// columns q*256 + lane*4 + e). q,e are wave-uniform -> scalar branches;
// only one lane writes. Static md indexing everywhere (rule #20).
__device__ __forceinline__ void set_inf(uint4 md[16], unsigned C, unsigned lane) {
  if (C >= 0x10000u) return;  // sentinel (first iteration)
  unsigned q = C >> 8, lt = (C >> 2) & 63, e = C & 3;
  unsigned iv = INFK(C);
  #pragma unroll
  for (unsigned qq = 0; qq < 16; ++qq) {
    if (qq == q && lane == lt) {
      if      (e == 0) md[qq].x = iv;
      else if (e == 1) md[qq].y = iv;
      else if (e == 2) md[qq].z = iv;
      else             md[qq].w = iv;
    }
  }
}

// ---------- fp32 -> bf16 conversion (8 elems/thread, grid-stride) ----------
__global__ __launch_bounds__(256) void cvt_bf16_kernel(const float* __restrict__ X,
                                                       short* __restrict__ Xb, int n8) {
  int stride = gridDim.x * 256;
  for (int i = blockIdx.x * 256 + threadIdx.x; i < n8; i += stride) {
    float4 a = *(const float4*)(X + (size_t)i * 8);
    float4 b = *(const float4*)(X + (size_t)i * 8 + 4);
    bf16x8 o;
    o[0] = f2bf(a.x); o[1] = f2bf(a.y); o[2] = f2bf(a.z); o[3] = f2bf(a.w);
    o[4] = f2bf(b.x); o[5] = f2bf(b.y); o[6] = f2bf(b.z); o[7] = f2bf(b.w);
    *(bf16x8*)(Xb + (size_t)i * 8) = o;
  }
}

// ---------- row squared norms (exact fp32) ----------
__global__ __launch_bounds__(256) void sqnorm_kernel(const float* __restrict__ X, int K,
                                                     float* __restrict__ sq) {
  int row = blockIdx.x;
  const float4* xr = (const float4*)(X + (size_t)row * K);
  float s = 0.f;
  int n4 = K >> 2;
  for (int i = threadIdx.x; i < n4; i += 256) {
    float4 v = xr[i];
    s += v.x * v.x + v.y * v.y + v.z * v.z + v.w * v.w;
  }
  for (int off = 32; off > 0; off >>= 1) s += __shfl_down(s, off);
  __shared__ float wsum[4];
  int lane = threadIdx.x & 63, w = threadIdx.x >> 6;
  if (lane == 0) wsum[w] = s;
  __syncthreads();
  if (threadIdx.x == 0) {
    float t = 0.f;
    #pragma unroll
    for (int i = 0; i < 4; ++i) t += wsum[i];
    sq[row] = t;
  }
}

// ---------- MFMA bf16 distance GEMM -> u32 argmin keys ----------
// K[i][j] = (halfbits(d_ij)<<16)|j, diagonal stored as INF-key (r13-proven).
__global__ __launch_bounds__(256) void dist_mfma_kernel(const short* __restrict__ Xb, int K,
                                                        const float* __restrict__ sq,
                                                        unsigned* __restrict__ Kd) {
  int t = blockIdx.x;
  int br = (int)((sqrtf(8.0f * (float)t + 1.0f) - 1.0f) * 0.5f);
  while ((br + 1) * (br + 2) / 2 <= t) ++br;
  while (br * (br + 1) / 2 > t) --br;
  int bc = t - br * (br + 1) / 2;
  int i0 = br * 128, j0 = bc * 128;

  __shared__ short As[128][40];
  __shared__ short Bs[128][40];

  int tid = threadIdx.x, lane = tid & 63, w = tid >> 6;
  int wr = w >> 1, wc = w & 1;
  int fr = lane & 15, fc = lane >> 4;

  f32x4 acc[4][4];
  #pragma unroll
  for (int m = 0; m < 4; ++m)
    #pragma unroll
    for (int nn = 0; nn < 4; ++nn)
      acc[m][nn] = (f32x4){0.f, 0.f, 0.f, 0.f};

  for (int k0 = 0; k0 < K; k0 += 32) {
    #pragma unroll
    for (int u = 0; u < 2; ++u) {
      int f = tid + u * 256;
      int r = f >> 2;
      int c = (f & 3) * 8;
      *(bf16x8*)&As[r][c] = *(const bf16x8*)(Xb + (size_t)(i0 + r) * K + k0 + c);
      *(bf16x8*)&Bs[r][c] = *(const bf16x8*)(Xb + (size_t)(j0 + r) * K + k0 + c);
    }
    __syncthreads();
    bf16x8 af[4], bg[4];
    #pragma unroll
    for (int m = 0; m < 4; ++m)
      af[m] = *(const bf16x8*)&As[wr * 64 + m * 16 + fr][fc * 8];
    #pragma unroll
    for (int nn = 0; nn < 4; ++nn)
      bg[nn] = *(const bf16x8*)&Bs[wc * 64 + nn * 16 + fr][fc * 8];
    #pragma unroll
    for (int m = 0; m < 4; ++m)
      #pragma unroll
      for (int nn = 0; nn < 4; ++nn)
        acc[m][nn] = __builtin_amdgcn_mfma_f32_16x16x32_bf16(af[m], bg[nn], acc[m][nn], 0, 0, 0);
    __syncthreads();
  }

  #pragma unroll
  for (int m = 0; m < 4; ++m) {
    #pragma unroll
    for (int nn = 0; nn < 4; ++nn) {
      int gj = j0 + wc * 64 + nn * 16 + fr;
      float sqj = sq[gj];
      #pragma unroll
      for (int e = 0; e < 4; ++e) {
        int gi = i0 + wr * 64 + m * 16 + fc * 4 + e;
        float d2 = sq[gi] + sqj - 2.0f * acc[m][nn][e];
        float d = sqrtf(fmaxf(d2, 0.0f));
        unsigned hb = (unsigned)__half_as_ushort(__float2half(d));
        unsigned kij = (gi == gj) ? INFK(gj) : ((hb << 16) | (unsigned)gj);
        unsigned kji = (gi == gj) ? INFK(gi) : ((hb << 16) | (unsigned)gi);
        Kd[(size_t)gi * N + gj] = kij;
        Kd[(size_t)gj * N + gi] = kji;
      }
    }
  }
}

// ---------- MST selection sequence: SINGLE WAVE per matrix ----------
// 64 lanes x 64 nodes/lane; md/prk/u all in registers (~250 VGPR).
// __launch_bounds__(64, 1): 1 wave/EU -> full 512-VGPR budget, no spill
// (r15's VGPR_Count=100 + scratch storm came from the default occupancy
// target). No LDS slots, no barrier, no cross-wave traffic.
__global__ __launch_bounds__(64, 1) void mst_seq1_kernel(const unsigned* __restrict__ Kx,
                                                         const unsigned* __restrict__ Kz,
                                                         unsigned* __restrict__ seqx,
                                                         unsigned* __restrict__ seqz) {
  const unsigned* __restrict__ Kd = (blockIdx.x == 0) ? Kx : Kz;
  unsigned* __restrict__ seqo = (blockIdx.x == 0) ? seqx : seqz;
  unsigned lane = threadIdx.x;   // 0..63
  unsigned co = lane * 4;        // column offset within each 256-wide chunk

  __shared__ unsigned seqlds[N - 1];

  uint4 md[16];
  #pragma unroll
  for (int q = 0; q < 16; ++q)
    md[q] = *(const uint4*)(Kd + q * 256 + co);   // row 0; diag INFK -> node 0 in tree

  unsigned j = wavemin(treemin16(md)) & 0xFFFFu;

  uint4 prk[16];
  #pragma unroll
  for (int q = 0; q < 16; ++q) prk[q] = make_uint4(~0u, ~0u, ~0u, ~0u);
  unsigned jprev = 0xFFFFFFFFu;  // sentinel

  for (int t = 0; t < N - 1; ++t) {
    // 1. issue the full-row load (16 x dwordx4, coalesced, 16 KB); pin order
    const unsigned* row = Kd + (size_t)j * N;
    uint4 u[16];
    #pragma unroll
    for (int q = 0; q < 16; ++q)
      u[q] = *(const uint4*)(row + q * 256 + co);
    __builtin_amdgcn_sched_barrier(0);

    // 2. record selection
    if (lane == 0) seqlds[t] = j;

    // 3. deferred update with previous row, then INF at j_{t-1}, then eager
    //    INF at j_t (r13-proven order) — all under the load
    #pragma unroll
    for (int q = 0; q < 16; ++q) {
      md[q].x = umin2(md[q].x, prk[q].x);
      md[q].y = umin2(md[q].y, prk[q].y);
      md[q].z = umin2(md[q].z, prk[q].z);
      md[q].w = umin2(md[q].w, prk[q].w);
    }
    set_inf(md, jprev, lane);
    set_inf(md, j, lane);

    // 4. A-tree over md (under load)
    unsigned ak = treemin16(md);

    // 5. B: per-q mins in load-arrival order, then tree (vmcnt lands here)
    unsigned bq[16];
    #pragma unroll
    for (int q = 0; q < 16; ++q)
      bq[q] = umin2(umin2(u[q].x, u[q].y), umin2(u[q].z, u[q].w));
    #pragma unroll
    for (int s = 8; s; s >>= 1)
      #pragma unroll
      for (int q2 = 0; q2 < s; ++q2) bq[q2] = umin2(bq[q2], bq[q2 + s]);

    // 6. ONE wavemin for A and B fused; next selection
    jprev = j;
    j = wavemin(umin2(ak, bq[0])) & 0xFFFFu;

    // 7. carry row for next step's deferred update
    #pragma unroll
    for (int q = 0; q < 16; ++q) prk[q] = u[q];
  }

  for (unsigned e = lane; e < N - 1; e += 64) seqo[e] = seqlds[e];
}

// ---------- parent reconstruction (r14-proven replay, 16-deep load pipeline) ----------
__global__ __launch_bounds__(512) void parent_kernel(const unsigned* __restrict__ Kx,
                                                     const unsigned* __restrict__ Kz,
                                                     const unsigned* __restrict__ seqx,
                                                     const unsigned* __restrict__ seqz,
                                                     int2* __restrict__ ex,
                                                     int2* __restrict__ ez) {
  int b = blockIdx.x;             // 0..15: 8 blocks per matrix
  bool isz = (b >= 8);
  const unsigned* __restrict__ Kd = isz ? Kz : Kx;
  const unsigned* __restrict__ seq = isz ? seqz : seqx;
  int2* __restrict__ edges = isz ? ez : ex;
  unsigned wn = (unsigned)(((b & 7) * 512) + threadIdx.x);  // node id

  __shared__ unsigned sseq[N - 1];
  for (int i = threadIdx.x; i < N - 1; i += 512) sseq[i] = seq[i];
  __syncthreads();

  unsigned md = Kd[wn];  // row 0; diag INFK gives md[0]="INF"
  int par = 0;

  // 16-deep pipeline: 16 independent loads in flight, then in-order process
  int t0 = 0;
  for (; t0 + 16 <= N - 1; t0 += 16) {
    unsigned r[16], v[16];
    #pragma unroll
    for (int k = 0; k < 16; ++k) {
      r[k] = sseq[t0 + k];
      v[k] = Kd[(size_t)r[k] * N + wn];
    }
    #pragma unroll
    for (int k = 0; k < 16; ++k) {
      if (r[k] == wn) edges[t0 + k] = make_int2(par, (int)wn);
      if (v[k] < md) { md = v[k]; par = (int)r[k]; }
      if (r[k] == wn) md = 0xFFFFFFFFu;
    }
  }
  for (int t = t0; t < N - 1; ++t) {
    unsigned r = sseq[t];
    if (r == wn) edges[t] = make_int2(par, (int)wn);
    unsigned v = Kd[(size_t)r * N + wn];
    if (v < md) { md = v; par = (int)r; }
    if (r == wn) md = 0xFFFFFFFFu;
  }
}

// ---------- final loss (reads u32 key matrices) ----------
__global__ __launch_bounds__(1024) void loss_kernel(const unsigned* __restrict__ KxM,
                                                    const unsigned* __restrict__ KzM,
                                                    const int2* __restrict__ ex,
                                                    const int2* __restrict__ ez,
                                                    float* __restrict__ out) {
  int tid = threadIdx.x;
  float s = 0.f;
  const int M = N - 1;
  for (int e = tid; e < 2 * M; e += 1024) {
    int2 uv = (e < M) ? ex[e] : ez[e - M];
    size_t off = (size_t)uv.x * N + uv.y;
    float dx = __half2float(__ushort_as_half((unsigned short)(KxM[off] >> 16)));
    float dz = __half2float(__ushort_as_half((unsigned short)(KzM[off] >> 16)));
    float d = dx - dz;
    s += d * d;
  }
  for (int off = 32; off > 0; off >>= 1) s += __shfl_down(s, off);
  __shared__ float wsum[16];
  int lane = tid & 63, w = tid >> 6;
  if (lane == 0) wsum[w] = s;
  __syncthreads();
  if (tid == 0) {
    float t = 0.f;
    #pragma unroll
    for (int i = 0; i < 16; ++i) t += wsum[i];
    out[0] = 0.5f * t;
  }
}

// ---------- launch ----------
extern "C" void kernel_launch(void* const* d_in, const int* in_sizes, int n_in,
                              void* d_out, int out_size, void* d_ws, size_t ws_size,
                              hipStream_t stream) {
  const float* x = (const float*)d_in[0];
  const float* z = (const float*)d_in[1];
  float* out = (float*)d_out;
  char* ws = (char*)d_ws;

  unsigned* Kx = (unsigned*)ws;                   // 64 MB
  unsigned* Kz = Kx + (size_t)N * N;              // 64 MB
  short* Xb = (short*)(Kz + (size_t)N * N);       // 24 MB
  short* Zb = Xb + (size_t)N * KX;                // 1 MB
  float* sqx = (float*)(Zb + (size_t)N * KZ);
  float* sqz = sqx + N;
  int2* ex = (int2*)(sqz + N);
  int2* ez = ex + (N - 1);
  // seq arrays alias Xb (free after the GEMMs read it; rewritten next launch)
  unsigned* seqx = (unsigned*)Xb;
  unsigned* seqz = seqx + (N - 1);

  cvt_bf16_kernel<<<2048, 256, 0, stream>>>(x, Xb, N * KX / 8);
  cvt_bf16_kernel<<<256, 256, 0, stream>>>(z, Zb, N * KZ / 8);
  sqnorm_kernel<<<N, 256, 0, stream>>>(x, KX, sqx);
  sqnorm_kernel<<<N, 256, 0, stream>>>(z, KZ, sqz);
  dist_mfma_kernel<<<NTRI2, 256, 0, stream>>>(Xb, KX, sqx, Kx);
  dist_mfma_kernel<<<NTRI2, 256, 0, stream>>>(Zb, KZ, sqz, Kz);
  mst_seq1_kernel<<<2, 64, 0, stream>>>(Kx, Kz, seqx, seqz);
  parent_kernel<<<16, 512, 0, stream>>>(Kx, Kz, seqx, seqz, ex, ez);
  loss_kernel<<<1, 1024, 0, stream>>>(Kx, Kz, ex, ez, out);
}

// Round 17
// 5534.600 us; speedup vs baseline: 1.0948x; 1.0005x over previous
//
#include <hip/hip_runtime.h>
#include <hip/hip_fp16.h>

#define N 4096
#define KX 3072
#define KZ 128
#define NBT (N / 128)               // 32 tile-rows for the MFMA dist kernel
#define NTRI2 (NBT * (NBT + 1) / 2) // 528 triangular tiles

typedef __attribute__((ext_vector_type(8))) short bf16x8;
typedef __attribute__((ext_vector_type(4))) float f32x4;

// ---------- helpers ----------
__device__ __forceinline__ short f2bf(float f) {  // RTN-even fp32 -> bf16
  unsigned u = __float_as_uint(f);
  u += 0x7fffu + ((u >> 16) & 1u);
  return (short)(u >> 16);
}

__device__ __forceinline__ unsigned umin2(unsigned a, unsigned b) { return a < b ? a : b; }

template <int CTRL>
__device__ __forceinline__ unsigned dpp_umin(unsigned x) {
  unsigned y = (unsigned)__builtin_amdgcn_update_dpp(0, (int)x, CTRL, 0xF, 0xF, true);
  return umin2(x, y);
}

#define INFK(idx) (0xFFFF0000u | (unsigned)(idx))

// wave-wide u32 min -> uniform value (4 DPP stages + readlane tail)
__device__ __forceinline__ unsigned wavemin(unsigned x) {
  x = dpp_umin<0xB1>(x);   // quad_perm [1,0,3,2]
  x = dpp_umin<0x4E>(x);   // quad_perm [2,3,0,1]
  x = dpp_umin<0x141>(x);  // row_half_mirror
  x = dpp_umin<0x140>(x);  // row_mirror
  unsigned r0 = (unsigned)__builtin_amdgcn_readlane((int)x, 0);
  unsigned r1 = (unsigned)__builtin_amdgcn_readlane((int)x, 16);
  unsigned r2 = (unsigned)__builtin_amdgcn_readlane((int)x, 32);
  unsigned r3 = (unsigned)__builtin_amdgcn_readlane((int)x, 48);
  return umin2(umin2(r0, r1), umin2(r2, r3));
}

// per-lane min over 16 uint4 (64 values), all static indexing
__device__ __forceinline__ unsigned treemin16(const uint4 m[16]) {
  unsigned a[16];
  #pragma unroll
  for (int q = 0; q < 16; ++q)
    a[q] = umin2(umin2(m[q].x, m[q].y), umin2(m[q].z, m[q].w));
  #pragma unroll
  for (int s = 8; s; s >>= 1)
    #pragma unroll
    for (int q = 0; q < s; ++q) a[q] = umin2(a[q], a[q + s]);
  return a[0];
}

// store INF-key at column C of the distributed md (layout: md[q] holds
// columns q*256 + lane*4 + e). q,e are wave-uniform -> scalar branches;
// only one lane writes. Static md indexing everywhere (rule #20).
__device__ __forceinline__ void set_inf(uint4 md[16], unsigned C, unsigned lane) {
  if (C >= 0x10000u) return;  // sentinel (first iteration)
  unsigned q = C >> 8, lt = (C >> 2) & 63, e = C & 3;
  unsigned iv = INFK(C);
  #pragma unroll
  for (unsigned qq = 0; qq < 16; ++qq) {
    if (qq == q && lane == lt) {
      if      (e == 0) md[qq].x = iv;
      else if (e == 1) md[qq].y = iv;
      else if (e == 2) md[qq].z = iv;
      else             md[qq].w = iv;
    }
  }
}

// ---------- fp32 -> bf16 conversion (8 elems/thread, grid-stride) ----------
__global__ __launch_bounds__(256) void cvt_bf16_kernel(const float* __restrict__ X,
                                                       short* __restrict__ Xb, int n8) {
  int stride = gridDim.x * 256;
  for (int i = blockIdx.x * 256 + threadIdx.x; i < n8; i += stride) {
    float4 a = *(const float4*)(X + (size_t)i * 8);
    float4 b = *(const float4*)(X + (size_t)i * 8 + 4);
    bf16x8 o;
    o[0] = f2bf(a.x); o[1] = f2bf(a.y); o[2] = f2bf(a.z); o[3] = f2bf(a.w);
    o[4] = f2bf(b.x); o[5] = f2bf(b.y); o[6] = f2bf(b.z); o[7] = f2bf(b.w);
    *(bf16x8*)(Xb + (size_t)i * 8) = o;
  }
}

// ---------- row squared norms (exact fp32) ----------
__global__ __launch_bounds__(256) void sqnorm_kernel(const float* __restrict__ X, int K,
                                                     float* __restrict__ sq) {
  int row = blockIdx.x;
  const float4* xr = (const float4*)(X + (size_t)row * K);
  float s = 0.f;
  int n4 = K >> 2;
  for (int i = threadIdx.x; i < n4; i += 256) {
    float4 v = xr[i];
    s += v.x * v.x + v.y * v.y + v.z * v.z + v.w * v.w;
  }
  for (int off = 32; off > 0; off >>= 1) s += __shfl_down(s, off);
  __shared__ float wsum[4];
  int lane = threadIdx.x & 63, w = threadIdx.x >> 6;
  if (lane == 0) wsum[w] = s;
  __syncthreads();
  if (threadIdx.x == 0) {
    float t = 0.f;
    #pragma unroll
    for (int i = 0; i < 4; ++i) t += wsum[i];
    sq[row] = t;
  }
}

// ---------- MFMA bf16 distance GEMM -> u32 argmin keys ----------
// K[i][j] = (halfbits(d_ij)<<16)|j, diagonal stored as INF-key (r13-proven).
__global__ __launch_bounds__(256) void dist_mfma_kernel(const short* __restrict__ Xb, int K,
                                                        const float* __restrict__ sq,
                                                        unsigned* __restrict__ Kd) {
  int t = blockIdx.x;
  int br = (int)((sqrtf(8.0f * (float)t + 1.0f) - 1.0f) * 0.5f);
  while ((br + 1) * (br + 2) / 2 <= t) ++br;
  while (br * (br + 1) / 2 > t) --br;
  int bc = t - br * (br + 1) / 2;
  int i0 = br * 128, j0 = bc * 128;

  __shared__ short As[128][40];
  __shared__ short Bs[128][40];

  int tid = threadIdx.x, lane = tid & 63, w = tid >> 6;
  int wr = w >> 1, wc = w & 1;
  int fr = lane & 15, fc = lane >> 4;

  f32x4 acc[4][4];
  #pragma unroll
  for (int m = 0; m < 4; ++m)
    #pragma unroll
    for (int nn = 0; nn < 4; ++nn)
      acc[m][nn] = (f32x4){0.f, 0.f, 0.f, 0.f};

  for (int k0 = 0; k0 < K; k0 += 32) {
    #pragma unroll
    for (int u = 0; u < 2; ++u) {
      int f = tid + u * 256;
      int r = f >> 2;
      int c = (f & 3) * 8;
      *(bf16x8*)&As[r][c] = *(const bf16x8*)(Xb + (size_t)(i0 + r) * K + k0 + c);
      *(bf16x8*)&Bs[r][c] = *(const bf16x8*)(Xb + (size_t)(j0 + r) * K + k0 + c);
    }
    __syncthreads();
    bf16x8 af[4], bg[4];
    #pragma unroll
    for (int m = 0; m < 4; ++m)
      af[m] = *(const bf16x8*)&As[wr * 64 + m * 16 + fr][fc * 8];
    #pragma unroll
    for (int nn = 0; nn < 4; ++nn)
      bg[nn] = *(const bf16x8*)&Bs[wc * 64 + nn * 16 + fr][fc * 8];
    #pragma unroll
    for (int m = 0; m < 4; ++m)
      #pragma unroll
      for (int nn = 0; nn < 4; ++nn)
        acc[m][nn] = __builtin_amdgcn_mfma_f32_16x16x32_bf16(af[m], bg[nn], acc[m][nn], 0, 0, 0);
    __syncthreads();
  }

  #pragma unroll
  for (int m = 0; m < 4; ++m) {
    #pragma unroll
    for (int nn = 0; nn < 4; ++nn) {
      int gj = j0 + wc * 64 + nn * 16 + fr;
      float sqj = sq[gj];
      #pragma unroll
      for (int e = 0; e < 4; ++e) {
        int gi = i0 + wr * 64 + m * 16 + fc * 4 + e;
        float d2 = sq[gi] + sqj - 2.0f * acc[m][nn][e];
        float d = sqrtf(fmaxf(d2, 0.0f));
        unsigned hb = (unsigned)__half_as_ushort(__float2half(d));
        unsigned kij = (gi == gj) ? INFK(gj) : ((hb << 16) | (unsigned)gj);
        unsigned kji = (gi == gj) ? INFK(gi) : ((hb << 16) | (unsigned)gi);
        Kd[(size_t)gi * N + gj] = kij;
        Kd[(size_t)gj * N + gi] = kji;
      }
    }
  }
}

// ---------- MST selection sequence: SINGLE WAVE per matrix ----------
// 64 lanes x 64 nodes/lane; md/prk/u in registers (~200 live + temps).
// amdgpu_waves_per_eu(1,1): min=max=1 wave/EU -> scheduler occupancy target 1,
// allocator budget 512 VGPRs, no spill. (r16's __launch_bounds__(64,1) was a
// no-op: the 2nd arg is a MINIMUM-occupancy register cap, min=1 = default.)
__global__ __attribute__((amdgpu_flat_work_group_size(64, 64), amdgpu_waves_per_eu(1, 1)))
void mst_seq1_kernel(const unsigned* __restrict__ Kx,
                     const unsigned* __restrict__ Kz,
                     unsigned* __restrict__ seqx,
                     unsigned* __restrict__ seqz) {
  const unsigned* __restrict__ Kd = (blockIdx.x == 0) ? Kx : Kz;
  unsigned* __restrict__ seqo = (blockIdx.x == 0) ? seqx : seqz;
  unsigned lane = threadIdx.x;   // 0..63
  unsigned co = lane * 4;        // column offset within each 256-wide chunk

  __shared__ unsigned seqlds[N - 1];

  uint4 md[16];
  #pragma unroll
  for (int q = 0; q < 16; ++q)
    md[q] = *(const uint4*)(Kd + q * 256 + co);   // row 0; diag INFK -> node 0 in tree

  unsigned j = wavemin(treemin16(md)) & 0xFFFFu;

  uint4 prk[16];
  #pragma unroll
  for (int q = 0; q < 16; ++q) prk[q] = make_uint4(~0u, ~0u, ~0u, ~0u);
  unsigned jprev = 0xFFFFFFFFu;  // sentinel

  for (int t = 0; t < N - 1; ++t) {
    // 1. issue the full-row load (16 x dwordx4, coalesced, 16 KB); pin order
    const unsigned* row = Kd + (size_t)j * N;
    uint4 u[16];
    #pragma unroll
    for (int q = 0; q < 16; ++q)
      u[q] = *(const uint4*)(row + q * 256 + co);
    __builtin_amdgcn_sched_barrier(0);

    // 2. record selection
    if (lane == 0) seqlds[t] = j;

    // 3. deferred update with previous row, then INF at j_{t-1}, then eager
    //    INF at j_t (r13-proven order) — all under the load
    #pragma unroll
    for (int q = 0; q < 16; ++q) {
      md[q].x = umin2(md[q].x, prk[q].x);
      md[q].y = umin2(md[q].y, prk[q].y);
      md[q].z = umin2(md[q].z, prk[q].z);
      md[q].w = umin2(md[q].w, prk[q].w);
    }
    set_inf(md, jprev, lane);
    set_inf(md, j, lane);

    // 4. A-tree over md (under load)
    unsigned ak = treemin16(md);

    // 5. B: per-q mins in load-arrival order, then tree (vmcnt lands here)
    unsigned bq[16];
    #pragma unroll
    for (int q = 0; q < 16; ++q)
      bq[q] = umin2(umin2(u[q].x, u[q].y), umin2(u[q].z, u[q].w));
    #pragma unroll
    for (int s = 8; s; s >>= 1)
      #pragma unroll
      for (int q2 = 0; q2 < s; ++q2) bq[q2] = umin2(bq[q2], bq[q2 + s]);

    // 6. ONE wavemin for A and B fused; next selection
    jprev = j;
    j = wavemin(umin2(ak, bq[0])) & 0xFFFFu;

    // 7. carry row for next step's deferred update
    #pragma unroll
    for (int q = 0; q < 16; ++q) prk[q] = u[q];
  }

  for (unsigned e = lane; e < N - 1; e += 64) seqo[e] = seqlds[e];
}

// ---------- parent reconstruction (r14-proven replay, 16-deep load pipeline) ----------
__global__ __launch_bounds__(512) void parent_kernel(const unsigned* __restrict__ Kx,
                                                     const unsigned* __restrict__ Kz,
                                                     const unsigned* __restrict__ seqx,
                                                     const unsigned* __restrict__ seqz,
                                                     int2* __restrict__ ex,
                                                     int2* __restrict__ ez) {
  int b = blockIdx.x;             // 0..15: 8 blocks per matrix
  bool isz = (b >= 8);
  const unsigned* __restrict__ Kd = isz ? Kz : Kx;
  const unsigned* __restrict__ seq = isz ? seqz : seqx;
  int2* __restrict__ edges = isz ? ez : ex;
  unsigned wn = (unsigned)(((b & 7) * 512) + threadIdx.x);  // node id

  __shared__ unsigned sseq[N - 1];
  for (int i = threadIdx.x; i < N - 1; i += 512) sseq[i] = seq[i];
  __syncthreads();

  unsigned md = Kd[wn];  // row 0; diag INFK gives md[0]="INF"
  int par = 0;

  // 16-deep pipeline: 16 independent loads in flight, then in-order process
  int t0 = 0;
  for (; t0 + 16 <= N - 1; t0 += 16) {
    unsigned r[16], v[16];
    #pragma unroll
    for (int k = 0; k < 16; ++k) {
      r[k] = sseq[t0 + k];
      v[k] = Kd[(size_t)r[k] * N + wn];
    }
    #pragma unroll
    for (int k = 0; k < 16; ++k) {
      if (r[k] == wn) edges[t0 + k] = make_int2(par, (int)wn);
      if (v[k] < md) { md = v[k]; par = (int)r[k]; }
      if (r[k] == wn) md = 0xFFFFFFFFu;
    }
  }
  for (int t = t0; t < N - 1; ++t) {
    unsigned r = sseq[t];
    if (r == wn) edges[t] = make_int2(par, (int)wn);
    unsigned v = Kd[(size_t)r * N + wn];
    if (v < md) { md = v; par = (int)r; }
    if (r == wn) md = 0xFFFFFFFFu;
  }
}

// ---------- final loss (reads u32 key matrices) ----------
__global__ __launch_bounds__(1024) void loss_kernel(const unsigned* __restrict__ KxM,
                                                    const unsigned* __restrict__ KzM,
                                                    const int2* __restrict__ ex,
                                                    const int2* __restrict__ ez,
                                                    float* __restrict__ out) {
  int tid = threadIdx.x;
  float s = 0.f;
  const int M = N - 1;
  for (int e = tid; e < 2 * M; e += 1024) {
    int2 uv = (e < M) ? ex[e] : ez[e - M];
    size_t off = (size_t)uv.x * N + uv.y;
    float dx = __half2float(__ushort_as_half((unsigned short)(KxM[off] >> 16)));
    float dz = __half2float(__ushort_as_half((unsigned short)(KzM[off] >> 16)));
    float d = dx - dz;
    s += d * d;
  }
  for (int off = 32; off > 0; off >>= 1) s += __shfl_down(s, off);
  __shared__ float wsum[16];
  int lane = tid & 63, w = tid >> 6;
  if (lane == 0) wsum[w] = s;
  __syncthreads();
  if (tid == 0) {
    float t = 0.f;
    #pragma unroll
    for (int i = 0; i < 16; ++i) t += wsum[i];
    out[0] = 0.5f * t;
  }
}

// ---------- launch ----------
extern "C" void kernel_launch(void* const* d_in, const int* in_sizes, int n_in,
                              void* d_out, int out_size, void* d_ws, size_t ws_size,
                              hipStream_t stream) {
  const float* x = (const float*)d_in[0];
  const float* z = (const float*)d_in[1];
  float* out = (float*)d_out;
  char* ws = (char*)d_ws;

  unsigned* Kx = (unsigned*)ws;                   // 64 MB
  unsigned* Kz = Kx + (size_t)N * N;              // 64 MB
  short* Xb = (short*)(Kz + (size_t)N * N);       // 24 MB
  short* Zb = Xb + (size_t)N * KX;                // 1 MB
  float* sqx = (float*)(Zb + (size_t)N * KZ);
  float* sqz = sqx + N;
  int2* ex = (int2*)(sqz + N);
  int2* ez = ex + (N - 1);
  // seq arrays alias Xb (free after the GEMMs read it; rewritten next launch)
  unsigned* seqx = (unsigned*)Xb;
  unsigned* seqz = seqx + (N - 1);

  cvt_bf16_kernel<<<2048, 256, 0, stream>>>(x, Xb, N * KX / 8);
  cvt_bf16_kernel<<<256, 256, 0, stream>>>(z, Zb, N * KZ / 8);
  sqnorm_kernel<<<N, 256, 0, stream>>>(x, KX, sqx);
  sqnorm_kernel<<<N, 256, 0, stream>>>(z, KZ, sqz);
  dist_mfma_kernel<<<NTRI2, 256, 0, stream>>>(Xb, KX, sqx, Kx);
  dist_mfma_kernel<<<NTRI2, 256, 0, stream>>>(Zb, KZ, sqz, Kz);
  mst_seq1_kernel<<<2, 64, 0, stream>>>(Kx, Kz, seqx, seqz);
  parent_kernel<<<16, 512, 0, stream>>>(Kx, Kz, seqx, seqz, ex, ez);
  loss_kernel<<<1, 1024, 0, stream>>>(Kx, Kz, ex, ez, out);
}

// Round 18
// 2225.090 us; speedup vs baseline: 2.7231x; 2.4874x over previous
//
#include <hip/hip_runtime.h>
#include <hip/hip_fp16.h>

#define N 4096
#define KX 3072
#define KZ 128
#define NBT (N / 128)               // 32 tile-rows for the MFMA dist kernel
#define NTRI2 (NBT * (NBT + 1) / 2) // 528 triangular tiles

typedef __attribute__((ext_vector_type(8))) short bf16x8;
typedef __attribute__((ext_vector_type(4))) float f32x4;

// ---------- helpers ----------
__device__ __forceinline__ short f2bf(float f) {  // RTN-even fp32 -> bf16
  unsigned u = __float_as_uint(f);
  u += 0x7fffu + ((u >> 16) & 1u);
  return (short)(u >> 16);
}

__device__ __forceinline__ unsigned umin2(unsigned a, unsigned b) { return a < b ? a : b; }

// DPP-based partial u32-min (within 16-lane rows); CTRL compile-time.
template <int CTRL>
__device__ __forceinline__ unsigned dpp_umin(unsigned x) {
  unsigned y = (unsigned)__builtin_amdgcn_update_dpp(0, (int)x, CTRL, 0xF, 0xF, true);
  return umin2(x, y);
}

#define INFK(idx) (0xFFFF0000u | (unsigned)(idx))

// ---------- fp32 -> bf16 conversion (8 elems/thread, grid-stride) ----------
__global__ __launch_bounds__(256) void cvt_bf16_kernel(const float* __restrict__ X,
                                                       short* __restrict__ Xb, int n8) {
  int stride = gridDim.x * 256;
  for (int i = blockIdx.x * 256 + threadIdx.x; i < n8; i += stride) {
    float4 a = *(const float4*)(X + (size_t)i * 8);
    float4 b = *(const float4*)(X + (size_t)i * 8 + 4);
    bf16x8 o;
    o[0] = f2bf(a.x); o[1] = f2bf(a.y); o[2] = f2bf(a.z); o[3] = f2bf(a.w);
    o[4] = f2bf(b.x); o[5] = f2bf(b.y); o[6] = f2bf(b.z); o[7] = f2bf(b.w);
    *(bf16x8*)(Xb + (size_t)i * 8) = o;
  }
}

// ---------- row squared norms (exact fp32) ----------
__global__ __launch_bounds__(256) void sqnorm_kernel(const float* __restrict__ X, int K,
                                                     float* __restrict__ sq) {
  int row = blockIdx.x;
  const float4* xr = (const float4*)(X + (size_t)row * K);
  float s = 0.f;
  int n4 = K >> 2;
  for (int i = threadIdx.x; i < n4; i += 256) {
    float4 v = xr[i];
    s += v.x * v.x + v.y * v.y + v.z * v.z + v.w * v.w;
  }
  for (int off = 32; off > 0; off >>= 1) s += __shfl_down(s, off);
  __shared__ float wsum[4];
  int lane = threadIdx.x & 63, w = threadIdx.x >> 6;
  if (lane == 0) wsum[w] = s;
  __syncthreads();
  if (threadIdx.x == 0) {
    float t = 0.f;
    #pragma unroll
    for (int i = 0; i < 4; ++i) t += wsum[i];
    sq[row] = t;
  }
}

// ---------- MFMA bf16 distance GEMM -> u32 argmin keys ----------
// K[i][j] = (halfbits(d_ij)<<16)|j, diagonal stored as INF-key
// (semantics-preserving: the suppressed self-parent par[j]=j can never reach
// an edge record — resurrection overwrites it before j can be re-selected).
__global__ __launch_bounds__(256) void dist_mfma_kernel(const short* __restrict__ Xb, int K,
                                                        const float* __restrict__ sq,
                                                        unsigned* __restrict__ Kd) {
  int t = blockIdx.x;
  int br = (int)((sqrtf(8.0f * (float)t + 1.0f) - 1.0f) * 0.5f);
  while ((br + 1) * (br + 2) / 2 <= t) ++br;
  while (br * (br + 1) / 2 > t) --br;
  int bc = t - br * (br + 1) / 2;
  int i0 = br * 128, j0 = bc * 128;

  __shared__ short As[128][40];
  __shared__ short Bs[128][40];

  int tid = threadIdx.x, lane = tid & 63, w = tid >> 6;
  int wr = w >> 1, wc = w & 1;
  int fr = lane & 15, fc = lane >> 4;

  f32x4 acc[4][4];
  #pragma unroll
  for (int m = 0; m < 4; ++m)
    #pragma unroll
    for (int nn = 0; nn < 4; ++nn)
      acc[m][nn] = (f32x4){0.f, 0.f, 0.f, 0.f};

  for (int k0 = 0; k0 < K; k0 += 32) {
    #pragma unroll
    for (int u = 0; u < 2; ++u) {
      int f = tid + u * 256;
      int r = f >> 2;
      int c = (f & 3) * 8;
      *(bf16x8*)&As[r][c] = *(const bf16x8*)(Xb + (size_t)(i0 + r) * K + k0 + c);
      *(bf16x8*)&Bs[r][c] = *(const bf16x8*)(Xb + (size_t)(j0 + r) * K + k0 + c);
    }
    __syncthreads();
    bf16x8 af[4], bg[4];
    #pragma unroll
    for (int m = 0; m < 4; ++m)
      af[m] = *(const bf16x8*)&As[wr * 64 + m * 16 + fr][fc * 8];
    #pragma unroll
    for (int nn = 0; nn < 4; ++nn)
      bg[nn] = *(const bf16x8*)&Bs[wc * 64 + nn * 16 + fr][fc * 8];
    #pragma unroll
    for (int m = 0; m < 4; ++m)
      #pragma unroll
      for (int nn = 0; nn < 4; ++nn)
        acc[m][nn] = __builtin_amdgcn_mfma_f32_16x16x32_bf16(af[m], bg[nn], acc[m][nn], 0, 0, 0);
    __syncthreads();
  }

  #pragma unroll
  for (int m = 0; m < 4; ++m) {
    #pragma unroll
    for (int nn = 0; nn < 4; ++nn) {
      int gj = j0 + wc * 64 + nn * 16 + fr;
      float sqj = sq[gj];
      #pragma unroll
      for (int e = 0; e < 4; ++e) {
        int gi = i0 + wr * 64 + m * 16 + fc * 4 + e;
        float d2 = sq[gi] + sqj - 2.0f * acc[m][nn][e];
        float d = sqrtf(fmaxf(d2, 0.0f));
        unsigned hb = (unsigned)__half_as_ushort(__float2half(d));
        unsigned kij = (gi == gj) ? INFK(gj) : ((hb << 16) | (unsigned)gj);
        unsigned kji = (gi == gj) ? INFK(gi) : ((hb << 16) | (unsigned)gi);
        Kd[(size_t)gi * N + gj] = kij;
        Kd[(size_t)gj * N + gi] = kji;
      }
    }
  }
}

// ---------- MST on precomputed keys (exact reference semantics; r13-proven) ----------
// 8 waves x 64 lanes x 8 nodes/thread. Deferred md/par update runs under the
// row-load latency (sched_barrier pins the load issue first); B-reduce operates
// directly on loaded keys (no building, no self-masking — diagonal is the
// stored INF-key). Edge recording in LDS, dumped once at the end. Single
// barrier per step; 8-slot u32-key combine (ties -> lowest index, exact).
__global__ __launch_bounds__(512) void mst_keys_kernel(const unsigned* __restrict__ Kx,
                                                       const unsigned* __restrict__ Kz,
                                                       int2* __restrict__ ex,
                                                       int2* __restrict__ ez) {
  const unsigned* __restrict__ Kd = (blockIdx.x == 0) ? Kx : Kz;
  int2* __restrict__ edges = (blockIdx.x == 0) ? ex : ez;

  int tid = threadIdx.x;      // 0..511
  int lane = tid & 63;
  int w = tid >> 6;           // wave 0..7
  int base = tid * 8;         // nodes [base, base+8)

  unsigned mdk0, mdk1, mdk2, mdk3, mdk4, mdk5, mdk6, mdk7;
  int par0 = 0, par1 = 0, par2 = 0, par3 = 0, par4 = 0, par5 = 0, par6 = 0, par7 = 0;
  {
    uint4 a = *(const uint4*)(Kd + base);
    uint4 b = *(const uint4*)(Kd + base + 4);
    mdk0 = a.x; mdk1 = a.y; mdk2 = a.z; mdk3 = a.w;
    mdk4 = b.x; mdk5 = b.y; mdk6 = b.z; mdk7 = b.w;
    // K[0][0] is the stored INF-key -> node 0 starts in tree automatically
  }

  __shared__ unsigned skey[2][8];
  __shared__ uint2 eld[N - 1];   // edge buffer (32 KB LDS)

  // ---- prologue: j0 = argmin(initial md)
  int j;
  {
    unsigned x = umin2(umin2(umin2(mdk0, mdk1), umin2(mdk2, mdk3)),
                       umin2(umin2(mdk4, mdk5), umin2(mdk6, mdk7)));
    x = dpp_umin<0xB1>(x);   // xor 1
    x = dpp_umin<0x4E>(x);   // xor 2
    x = dpp_umin<0x141>(x);  // xor 4 (row_half_mirror)
    x = dpp_umin<0x140>(x);  // xor 8 (row_mirror)
    unsigned r0 = (unsigned)__builtin_amdgcn_readlane((int)x, 0);
    unsigned r1 = (unsigned)__builtin_amdgcn_readlane((int)x, 16);
    unsigned r2 = (unsigned)__builtin_amdgcn_readlane((int)x, 32);
    unsigned r3 = (unsigned)__builtin_amdgcn_readlane((int)x, 48);
    unsigned wm = umin2(umin2(r0, r1), umin2(r2, r3));
    if (lane == 0) skey[1][w] = wm;
    __syncthreads();
    uint4 A = ((const uint4*)&skey[1][0])[0];
    uint4 B = ((const uint4*)&skey[1][0])[1];
    unsigned k = umin2(umin2(umin2(A.x, A.y), umin2(A.z, A.w)),
                       umin2(umin2(B.x, B.y), umin2(B.z, B.w)));
    j = (int)(k & 0xFFFFu);
  }

  // carried state: previous row keys + its position
  unsigned prk0 = 0xFFFFFFFFu, prk1 = 0xFFFFFFFFu, prk2 = 0xFFFFFFFFu, prk3 = 0xFFFFFFFFu,
           prk4 = 0xFFFFFFFFu, prk5 = 0xFFFFFFFFu, prk6 = 0xFFFFFFFFu, prk7 = 0xFFFFFFFFu;
  int jp = 0, jtprev = -1, jlprev = 0;

  for (int t = 0; t < N - 1; ++t) {
    int p = t & 1;
    int jt = j >> 3, jl = j & 7;

    // 1. issue this step's row load (keys, 32B/thread); pin issue order
    const unsigned* row = Kd + (size_t)j * N + base;
    uint4 ua = *(const uint4*)row;
    uint4 ub = *(const uint4*)(row + 4);
    __builtin_amdgcn_sched_barrier(0);

    // 2. deferred md/par update with PREVIOUS row (reference step t-1 tail)
    #define DUPD(q) { bool up_ = prk##q < mdk##q; mdk##q = up_ ? prk##q : mdk##q; par##q = up_ ? jp : par##q; }
    DUPD(0) DUPD(1) DUPD(2) DUPD(3) DUPD(4) DUPD(5) DUPD(6) DUPD(7)
    #undef DUPD
    if (jtprev == tid) {   // re-INF at j_{t-1} (after min, like .at[j].set(inf))
      if      (jlprev == 0) mdk0 = INFK(base + 0);
      else if (jlprev == 1) mdk1 = INFK(base + 1);
      else if (jlprev == 2) mdk2 = INFK(base + 2);
      else if (jlprev == 3) mdk3 = INFK(base + 3);
      else if (jlprev == 4) mdk4 = INFK(base + 4);
      else if (jlprev == 5) mdk5 = INFK(base + 5);
      else if (jlprev == 6) mdk6 = INFK(base + 6);
      else                  mdk7 = INFK(base + 7);
    }

    // 3. record edge t into LDS (par == reference parent state at start of t)
    if (jt == tid) {
      int pj = (jl == 0) ? par0 : (jl == 1) ? par1 : (jl == 2) ? par2 :
               (jl == 3) ? par3 : (jl == 4) ? par4 : (jl == 5) ? par5 :
               (jl == 6) ? par6 : par7;
      eld[t] = make_uint2((unsigned)pj, (unsigned)j);
    }

    // 4. eager INF at current j
    if (jt == tid) {
      if      (jl == 0) mdk0 = INFK(base + 0);
      else if (jl == 1) mdk1 = INFK(base + 1);
      else if (jl == 2) mdk2 = INFK(base + 2);
      else if (jl == 3) mdk3 = INFK(base + 3);
      else if (jl == 4) mdk4 = INFK(base + 4);
      else if (jl == 5) mdk5 = INFK(base + 5);
      else if (jl == 6) mdk6 = INFK(base + 6);
      else              mdk7 = INFK(base + 7);
    }

    // 5. A-tree over md keys (pure VALU, hidden under load)
    unsigned ak = umin2(umin2(umin2(mdk0, mdk1), umin2(mdk2, mdk3)),
                        umin2(umin2(mdk4, mdk5), umin2(mdk6, mdk7)));

    // 6. B-tree directly on loaded keys (first use of ua/ub waits here)
    {
      unsigned bk = umin2(umin2(umin2(ua.x, ua.y), umin2(ua.z, ua.w)),
                          umin2(umin2(ub.x, ub.y), umin2(ub.z, ub.w)));
      unsigned x = umin2(ak, bk);
      x = dpp_umin<0xB1>(x);
      x = dpp_umin<0x4E>(x);
      x = dpp_umin<0x141>(x);
      x = dpp_umin<0x140>(x);
      unsigned r0 = (unsigned)__builtin_amdgcn_readlane((int)x, 0);
      unsigned r1 = (unsigned)__builtin_amdgcn_readlane((int)x, 16);
      unsigned r2 = (unsigned)__builtin_amdgcn_readlane((int)x, 32);
      unsigned r3 = (unsigned)__builtin_amdgcn_readlane((int)x, 48);
      unsigned wm = umin2(umin2(r0, r1), umin2(r2, r3));
      if (lane == 0) skey[p][w] = wm;
    }

    // 7. carry row keys for next step's deferred update
    prk0 = ua.x; prk1 = ua.y; prk2 = ua.z; prk3 = ua.w;
    prk4 = ub.x; prk5 = ub.y; prk6 = ub.z; prk7 = ub.w;
    jp = j; jtprev = jt; jlprev = jl;

    // 8. single barrier; 8-slot u32 combine
    __syncthreads();
    uint4 A = ((const uint4*)&skey[p][0])[0];
    uint4 B = ((const uint4*)&skey[p][0])[1];
    unsigned k = umin2(umin2(umin2(A.x, A.y), umin2(A.z, A.w)),
                       umin2(umin2(B.x, B.y), umin2(B.z, B.w)));
    j = (int)(k & 0xFFFFu);
  }

  // ---- dump edges LDS -> global (coalesced)
  __syncthreads();
  for (int e = tid; e < N - 1; e += 512) {
    uint2 v = eld[e];
    edges[e] = make_int2((int)v.x, (int)v.y);
  }
}

// ---------- final loss (reads u32 key matrices) ----------
__global__ __launch_bounds__(1024) void loss_kernel(const unsigned* __restrict__ KxM,
                                                    const unsigned* __restrict__ KzM,
                                                    const int2* __restrict__ ex,
                                                    const int2* __restrict__ ez,
                                                    float* __restrict__ out) {
  int tid = threadIdx.x;
  float s = 0.f;
  const int M = N - 1;
  for (int e = tid; e < 2 * M; e += 1024) {
    int2 uv = (e < M) ? ex[e] : ez[e - M];
    size_t off = (size_t)uv.x * N + uv.y;
    float dx = __half2float(__ushort_as_half((unsigned short)(KxM[off] >> 16)));
    float dz = __half2float(__ushort_as_half((unsigned short)(KzM[off] >> 16)));
    float d = dx - dz;
    s += d * d;
  }
  for (int off = 32; off > 0; off >>= 1) s += __shfl_down(s, off);
  __shared__ float wsum[16];
  int lane = tid & 63, w = tid >> 6;
  if (lane == 0) wsum[w] = s;
  __syncthreads();
  if (tid == 0) {
    float t = 0.f;
    #pragma unroll
    for (int i = 0; i < 16; ++i) t += wsum[i];
    out[0] = 0.5f * t;
  }
}

// ---------- launch ----------
extern "C" void kernel_launch(void* const* d_in, const int* in_sizes, int n_in,
                              void* d_out, int out_size, void* d_ws, size_t ws_size,
                              hipStream_t stream) {
  const float* x = (const float*)d_in[0];
  const float* z = (const float*)d_in[1];
  float* out = (float*)d_out;
  char* ws = (char*)d_ws;

  unsigned* Kx = (unsigned*)ws;                   // 64 MB
  unsigned* Kz = Kx + (size_t)N * N;              // 64 MB
  short* Xb = (short*)(Kz + (size_t)N * N);       // 24 MB
  short* Zb = Xb + (size_t)N * KX;                // 1 MB
  float* sqx = (float*)(Zb + (size_t)N * KZ);
  float* sqz = sqx + N;
  int2* ex = (int2*)(sqz + N);
  int2* ez = ex + (N - 1);

  cvt_bf16_kernel<<<2048, 256, 0, stream>>>(x, Xb, N * KX / 8);
  cvt_bf16_kernel<<<256, 256, 0, stream>>>(z, Zb, N * KZ / 8);
  sqnorm_kernel<<<N, 256, 0, stream>>>(x, KX, sqx);
  sqnorm_kernel<<<N, 256, 0, stream>>>(z, KZ, sqz);
  dist_mfma_kernel<<<NTRI2, 256, 0, stream>>>(Xb, KX, sqx, Kx);
  dist_mfma_kernel<<<NTRI2, 256, 0, stream>>>(Zb, KZ, sqz, Kz);
  mst_keys_kernel<<<2, 512, 0, stream>>>(Kx, Kz, ex, ez);
  loss_kernel<<<1, 1024, 0, stream>>>(Kx, Kz, ex, ez, out);
}